// Round 13
// baseline (482.442 us; speedup 1.0000x reference)
//
#include <hip/hip_runtime.h>
#include <stdint.h>

#define NN 100000     // nodes
#define NE 1600000    // edges
#define DD 128        // feature dim
#define NL 3          // layers
#define NG 2048       // graphs
#define BN_EPS 1e-5f
#define CAP 56        // per-node bucket capacity (Poisson(16); P(deg>=56)*NN ~ 8e-9)
#define GSH 9         // node-group shift: 512 nodes per group
#define GSZ 512
#define NGRP 196      // ceil(NN/512)
#define GBINCAP 9216  // per-group edge bin capacity (mean 8192, sigma~90 -> +11 sigma)
#define MAXSEG 16     // max graph segments per 128-row MLP block (LDS path)
#define NSLOT 64      // stats partial slots (contention 782/64 ~ 12-deep)

typedef short s16x8 __attribute__((ext_vector_type(8)));
typedef float f32x4 __attribute__((ext_vector_type(4)));
typedef float f32x2 __attribute__((ext_vector_type(2)));

__device__ __forceinline__ unsigned short f2bfu(float f) {
    union { float f; unsigned int i; } x; x.f = f;
    unsigned int r = x.i + 0x7fffu + ((x.i >> 16) & 1u);
    return (unsigned short)(r >> 16);
}
__device__ __forceinline__ float bfu2f(unsigned short u) {
    union { unsigned int i; float f; } x; x.i = ((unsigned int)u) << 16; return x.f;
}
__device__ __forceinline__ float uplo(unsigned int u) {
    union { unsigned int i; float f; } x; x.i = u << 16; return x.f;
}
__device__ __forceinline__ float uphi(unsigned int u) {
    union { unsigned int i; float f; } x; x.i = u & 0xffff0000u; return x.f;
}
// bf16 pair (lo,hi of one u32) -> f32x2; vector += maps to v_pk_add_f32.
__device__ __forceinline__ f32x2 up2(unsigned int u) {
    union { unsigned int i; float f; } lo, hi;
    lo.i = u << 16; hi.i = u & 0xffff0000u;
    f32x2 r; r[0] = lo.f; r[1] = hi.f;
    return r;
}
__device__ __forceinline__ unsigned int pack2(float a, float b) {
    return (unsigned int)f2bfu(a) | ((unsigned int)f2bfu(b) << 16);
}

// ---------------------------------------------------------------------------
// One-time: x (f32) -> hb (bf16).
__global__ __launch_bounds__(256) void k_cvt(
    const float* __restrict__ x, unsigned short* __restrict__ hb)
{
    int i = (blockIdx.x * 256 + threadIdx.x) * 4;
    if (i >= NN * DD) return;
    float4 v = *(const float4*)(x + i);
    ushort4 o;
    o.x = f2bfu(v.x); o.y = f2bfu(v.y); o.z = f2bfu(v.z); o.w = f2bfu(v.w);
    *(ushort4*)(hb + i) = o;
}

// ---------------------------------------------------------------------------
// W1/W2 f32 [L][k][n] -> bf16 Wt[mat][n][k] (transposed for MFMA B operand).
__global__ __launch_bounds__(256) void k_wtrans(
    const float* __restrict__ W1, const float* __restrict__ W2,
    unsigned short* __restrict__ Wt)
{
    int idx = blockIdx.x * 256 + threadIdx.x;
    if (idx >= 6 * DD * DD) return;
    int mat = idx >> 14;
    int r = idx & 16383;
    int n = r >> 7, k = r & 127;
    const float* src = (mat < 3) ? (W1 + mat * DD * DD) : (W2 + (mat - 3) * DD * DD);
    Wt[idx] = f2bfu(src[k * DD + n]);
}

// ---------------------------------------------------------------------------
// batch (sorted int32) -> graph start offsets; start[NG] = NN.
__global__ __launch_bounds__(256) void k_bounds(
    const int* __restrict__ batch, int* __restrict__ start)
{
    int n = blockIdx.x * 256 + threadIdx.x;
    if (n >= NN) return;
    int bn = batch[n];
    bn = bn < 0 ? 0 : (bn > NG - 1 ? NG - 1 : bn);
    int bp;
    if (n == 0) bp = -1;
    else {
        bp = batch[n - 1];
        bp = bp < 0 ? 0 : (bp > NG - 1 ? NG - 1 : bp);
    }
    for (int g = bp + 1; g <= bn; ++g) start[g] = n;
    if (n == NN - 1) {
        for (int g = bn + 1; g <= NG; ++g) start[g] = NN;
    }
}

// ---------------------------------------------------------------------------
// Stage 1: single scan of ei; in-LDS counting sort of 4096 edges/block into
// NGRP node-groups; flush each group's edges as a CONTIGUOUS chunk at an
// atomically reserved offset. Packed record: (local_dst[9] << 17) | src[17].
__global__ __launch_bounds__(256) void k_grp(
    const int* __restrict__ ei, int* __restrict__ gcnt,
    unsigned int* __restrict__ bins)
{
    __shared__ int hist[256];
    __shared__ int scn[256];
    __shared__ int exs[256];
    __shared__ int lofs[256];
    __shared__ int gbase[256];
    __shared__ unsigned int stage[4096];
    const int tid = threadIdx.x;
    hist[tid] = 0;
    __syncthreads();

    // Phase A: load 16 edges/thread, histogram groups.
    unsigned int pk[16];
    int gg[16];
    unsigned int vmask = 0;
    #pragma unroll
    for (int q = 0; q < 4; ++q) {
        long long e0 = (long long)blockIdx.x * 4096 + q * 1024 + tid * 4;
        if (e0 < NE) {     // NE % 4 == 0: quad fully in range
            const int* dp = ei + NE + e0;
            const int* sp = ei + e0;
            int dd_[4], ss_[4];
            dd_[0] = __builtin_nontemporal_load(dp + 0);
            dd_[1] = __builtin_nontemporal_load(dp + 1);
            dd_[2] = __builtin_nontemporal_load(dp + 2);
            dd_[3] = __builtin_nontemporal_load(dp + 3);
            ss_[0] = __builtin_nontemporal_load(sp + 0);
            ss_[1] = __builtin_nontemporal_load(sp + 1);
            ss_[2] = __builtin_nontemporal_load(sp + 2);
            ss_[3] = __builtin_nontemporal_load(sp + 3);
            #pragma unroll
            for (int i = 0; i < 4; ++i) {
                int dst = dd_[i], src = ss_[i];
                if ((unsigned)dst < NN && (unsigned)src < NN) {
                    int g = dst >> GSH;
                    int j = q * 4 + i;
                    pk[j] = ((unsigned)(dst & (GSZ - 1)) << 17) | (unsigned)src;
                    gg[j] = g;
                    atomicAdd(&hist[g], 1);
                    vmask |= 1u << j;
                }
            }
        }
    }
    __syncthreads();

    // Phase B: exclusive prefix over 256 group counters (Hillis-Steele).
    int v = hist[tid];
    scn[tid] = v;
    __syncthreads();
    #pragma unroll
    for (int off = 1; off < 256; off <<= 1) {
        int t = (tid >= off) ? scn[tid - off] : 0;
        __syncthreads();
        scn[tid] += t;
        __syncthreads();
    }
    int ex = scn[tid] - v;
    exs[tid] = ex;
    lofs[tid] = ex;
    if (tid < NGRP) {
        gbase[tid] = hist[tid] ? atomicAdd(&gcnt[tid], hist[tid]) : 0;
    }
    __syncthreads();

    // Phase C: scatter into LDS staging (group-sorted order).
    #pragma unroll
    for (int j = 0; j < 16; ++j) {
        if (vmask & (1u << j)) {
            int p = atomicAdd(&lofs[gg[j]], 1);
            stage[p] = pk[j];
        }
    }
    __syncthreads();

    // Phase D: per-wave coalesced chunk flush, one group at a time.
    const int wave = tid >> 6, lane = tid & 63;
    for (int g = wave; g < NGRP; g += 4) {
        int len = hist[g];
        if (!len) continue;
        int gb = gbase[g], pb = exs[g];
        for (int k = lane; k < len; k += 64) {
            int o = gb + k;
            if (o < GBINCAP)
                bins[(long long)g * GBINCAP + o] = stage[pb + k];
        }
    }
}

// ---------------------------------------------------------------------------
// Stage 2: one block per 512-node group. Bucket fill entirely in LDS; global
// side is a coalesced bin read + fully coalesced csr region write.
__global__ __launch_bounds__(256, 1) void k_csr(
    const int* __restrict__ gcnt, const unsigned int* __restrict__ bins,
    int* __restrict__ cnt, int* __restrict__ csr)
{
    __shared__ int lcnt[GSZ];
    __shared__ int lcsr[GSZ * CAP];    // 512*56*4 = 114,688 B
    const int g = blockIdx.x;
    const int tid = threadIdx.x;
    for (int i = tid; i < GSZ; i += 256) lcnt[i] = 0;
    __syncthreads();

    int count = gcnt[g];
    count = count > GBINCAP ? GBINCAP : count;
    const unsigned int* bp = bins + (long long)g * GBINCAP;
    for (int e = tid * 4; e < count; e += 1024) {
        if (e + 4 <= count) {
            uint4 q4;
            q4.x = __builtin_nontemporal_load(bp + e + 0);
            q4.y = __builtin_nontemporal_load(bp + e + 1);
            q4.z = __builtin_nontemporal_load(bp + e + 2);
            q4.w = __builtin_nontemporal_load(bp + e + 3);
            unsigned int u[4] = {q4.x, q4.y, q4.z, q4.w};
            #pragma unroll
            for (int i = 0; i < 4; ++i) {
                int local = (int)(u[i] >> 17);
                int src = (int)(u[i] & 0x1FFFFu);
                int pos = atomicAdd(&lcnt[local], 1);
                if (pos < CAP) lcsr[local * CAP + pos] = src;
            }
        } else {
            for (int i = e; i < count; ++i) {
                unsigned int u = bp[i];
                int local = (int)(u >> 17);
                int src = (int)(u & 0x1FFFFu);
                int pos = atomicAdd(&lcnt[local], 1);
                if (pos < CAP) lcsr[local * CAP + pos] = src;
            }
        }
    }
    __syncthreads();

    const int nbase = g << GSH;
    int nmax = NN - nbase;
    nmax = nmax > GSZ ? GSZ : nmax;
    for (int i = tid; i < nmax; i += 256) cnt[nbase + i] = lcnt[i];
    const int tot = nmax * CAP;            // multiple of 4 (CAP=56)
    int* dstp = csr + (long long)nbase * CAP;
    for (int i = tid * 4; i < tot; i += 1024)
        *(int4*)(dstp + i) = *(const int4*)(&lcsr[i]);
}

// ---------------------------------------------------------------------------
// Gather-aggregate with BN-affine fold. 16-deep load batches (round-5 proven).
// CHANGE: packed f32x2 accumulation (v_pk_add/fma_f32) — 12 VALU slots per
// uint4 instead of 16; VALU was co-pacing the gather (46% VALUBusy, r12).
// Per-dim add order unchanged -> bit-identical results.
template <bool L0>
__global__ __launch_bounds__(256) void k_agg(
    const unsigned short* __restrict__ hb, const int* __restrict__ cnt,
    const int* __restrict__ csr, unsigned short* __restrict__ aggf,
    const float* __restrict__ stats_prev, const float* __restrict__ gamma_prev,
    const float* __restrict__ beta_prev)
{
    const int node = blockIdx.x * 16 + (threadIdx.x >> 4);
    const int lane = threadIdx.x & 15;
    if (node >= NN) return;
    int deg = cnt[node];
    deg = deg > CAP ? CAP : deg;
    const int* bkt = csr + node * CAP;
    const unsigned short* base = hb + lane * 8;
    f32x2 self2[4], acc2[4];
    {
        uint4 v = *(const uint4*)(base + (long long)node * DD);   // self
        self2[0] = up2(v.x); self2[1] = up2(v.y);
        self2[2] = up2(v.z); self2[3] = up2(v.w);
        #pragma unroll
        for (int j = 0; j < 4; ++j) acc2[j] = self2[j];
    }
    const int nb = (deg + 15) >> 4;
    for (int b = 0; b < nb; ++b) {
        const int e0 = b * 16;
        // NOTE: may read up to bkt[63] (past CAP for deg>=49); lands in the
        // following csr bucket — safe, and those indices are never used.
        int4 i0 = *(const int4*)(bkt + e0);
        int4 i1 = *(const int4*)(bkt + e0 + 4);
        int4 i2 = *(const int4*)(bkt + e0 + 8);
        int4 i3 = *(const int4*)(bkt + e0 + 12);
        int idx[16] = {i0.x, i0.y, i0.z, i0.w, i1.x, i1.y, i1.z, i1.w,
                       i2.x, i2.y, i2.z, i2.w, i3.x, i3.y, i3.z, i3.w};
        uint4 v[16];
        #pragma unroll
        for (int i = 0; i < 16; ++i) {
            int id = (e0 + i < deg) ? idx[i] : node;
            v[i] = *(const uint4*)(base + (long long)id * DD);
        }
        #pragma unroll
        for (int i = 0; i < 16; ++i) {
            acc2[0] += up2(v[i].x);
            acc2[1] += up2(v[i].y);
            acc2[2] += up2(v[i].z);
            acc2[3] += up2(v[i].w);
        }
    }
    int pad = nb * 16 - deg;
    if (pad) {
        float pf = (float)pad;
        #pragma unroll
        for (int j = 0; j < 4; ++j) acc2[j] += -pf * self2[j];   // v_pk_fma
    }
    if (!L0) {
        const float inv_n = 1.0f / (float)NN;
        const float dp1 = (float)(deg + 1);
        #pragma unroll
        for (int j = 0; j < 8; ++j) {
            int d = lane * 8 + j;
            float mean = stats_prev[d] * inv_n;
            float var = stats_prev[DD + d] * inv_n - mean * mean;
            float inv = rsqrtf(fmaxf(var, 0.f) + BN_EPS);
            float a = gamma_prev[d] * inv;
            float c = beta_prev[d] - mean * a;
            acc2[j >> 1][j & 1] = a * acc2[j >> 1][j & 1] + c * dp1;
        }
    }
    uint4 o;
    o.x = pack2(acc2[0][0], acc2[0][1]);
    o.y = pack2(acc2[1][0], acc2[1][1]);
    o.z = pack2(acc2[2][0], acc2[2][1]);
    o.w = pack2(acc2[3][0], acc2[3][1]);
    *(uint4*)(aggf + (long long)node * DD + lane * 8) = o;
}

// ---------------------------------------------------------------------------
// Fused MLP + BN stats + per-graph segment max/min (round-12 base).
// CHANGE: k_red fused as a LAST-BLOCK reduction (device-scope counter dcnt;
// __syncthreads drains each wave's atomics to L2 before the counter bump) —
// removes 3 k_red launches and their pipeline bubbles.
template <bool WRH>
__global__ __launch_bounds__(256, 3) void k_mlp(
    const unsigned short* __restrict__ aggf, unsigned short* __restrict__ hout,
    const unsigned short* __restrict__ W1t, const float* __restrict__ b1,
    const unsigned short* __restrict__ W2t, const float* __restrict__ b2,
    float* __restrict__ statsP, float* __restrict__ stats,
    int* __restrict__ dcnt, const int* __restrict__ batch,
    unsigned int* __restrict__ gmxl, unsigned int* __restrict__ gmnl)
{
    __shared__ unsigned short lA[128 * 136];   // 34,816 B (+8 pad rows)
    __shared__ unsigned short lW[128 * 68];    // 17,408 B: half-K W tile
    __shared__ int sB[128];
    __shared__ bool sLast;
    const int tid = threadIdx.x;
    const int row0 = blockIdx.x * 128;

    if (tid < 128) {
        int row = row0 + tid;
        int b = batch[row < NN ? row : NN - 1];
        b = b < 0 ? 0 : (b > NG - 1 ? NG - 1 : b);
        sB[tid] = b;
    }
    {   // A tile from aggf
        int col8 = tid & 15, rr = tid >> 4;
        #pragma unroll
        for (int it = 0; it < 8; ++it) {
            int r = rr + it * 16;
            int grow = row0 + r;
            uint4 v;
            if (grow < NN) {
                v = *(const uint4*)(aggf + (long long)grow * DD + col8 * 8);
            } else {
                v.x = v.y = v.z = v.w = 0;
            }
            *(uint4*)(&lA[r * 136 + col8 * 8]) = v;
        }
    }

    const int wave = tid >> 6, lane = tid & 63;
    const int quad = lane >> 4, m16 = lane & 15;

    // ---- pass 1: M1 = A @ W1 (two half-K stages) ----
    f32x4 acc[2][8] = {};
    #pragma unroll
    for (int kh = 0; kh < 2; ++kh) {
        #pragma unroll
        for (int it = 0; it < 4; ++it) {            // stage 128x64 half of W1
            int eidx = (it * 256 + tid) * 8;        // 0..8191
            int r = eidx >> 6, c = eidx & 63;
            *(uint4*)(&lW[r * 68 + c]) = *(const uint4*)(W1t + r * DD + kh * 64 + c);
        }
        __syncthreads();                            // staging (and A tile) ready
        #pragma unroll
        for (int k0i = 0; k0i < 2; ++k0i) {
            const int kkA = kh * 64 + k0i * 32 + quad * 8;
            const int kkW = k0i * 32 + quad * 8;
            s16x8 a0 = *(const s16x8*)(&lA[(wave * 32 + m16) * 136 + kkA]);
            s16x8 a1 = *(const s16x8*)(&lA[(wave * 32 + 16 + m16) * 136 + kkA]);
            #pragma unroll
            for (int ct = 0; ct < 8; ++ct) {
                s16x8 bf = *(const s16x8*)(&lW[(ct * 16 + m16) * 68 + kkW]);
                acc[0][ct] = __builtin_amdgcn_mfma_f32_16x16x32_bf16(a0, bf, acc[0][ct], 0, 0, 0);
                acc[1][ct] = __builtin_amdgcn_mfma_f32_16x16x32_bf16(a1, bf, acc[1][ct], 0, 0, 0);
            }
        }
        __syncthreads();                            // reads done before restage
    }

    // relu(M1 + b1) back into lA. C/D map: col = lane&15, row = quad*4 + reg.
    #pragma unroll
    for (int rt = 0; rt < 2; ++rt) {
        #pragma unroll
        for (int ct = 0; ct < 8; ++ct) {
            int col = ct * 16 + m16;
            float b = b1[col];
            #pragma unroll
            for (int r = 0; r < 4; ++r) {
                int lrow = wave * 32 + rt * 16 + quad * 4 + r;
                lA[lrow * 136 + col] = f2bfu(fmaxf(acc[rt][ct][r] + b, 0.0f));
            }
        }
    }

    // ---- pass 2: M2 = M1 @ W2 (two half-K stages) ----
    #pragma unroll
    for (int rt = 0; rt < 2; ++rt)
        #pragma unroll
        for (int ct = 0; ct < 8; ++ct)
            acc[rt][ct] = f32x4{0.f, 0.f, 0.f, 0.f};
    #pragma unroll
    for (int kh = 0; kh < 2; ++kh) {
        #pragma unroll
        for (int it = 0; it < 4; ++it) {            // stage 128x64 half of W2
            int eidx = (it * 256 + tid) * 8;
            int r = eidx >> 6, c = eidx & 63;
            *(uint4*)(&lW[r * 68 + c]) = *(const uint4*)(W2t + r * DD + kh * 64 + c);
        }
        __syncthreads();                            // staging + (kh=0) relu-writes ready
        #pragma unroll
        for (int k0i = 0; k0i < 2; ++k0i) {
            const int kkA = kh * 64 + k0i * 32 + quad * 8;
            const int kkW = k0i * 32 + quad * 8;
            s16x8 a0 = *(const s16x8*)(&lA[(wave * 32 + m16) * 136 + kkA]);
            s16x8 a1 = *(const s16x8*)(&lA[(wave * 32 + 16 + m16) * 136 + kkA]);
            #pragma unroll
            for (int ct = 0; ct < 8; ++ct) {
                s16x8 bf = *(const s16x8*)(&lW[(ct * 16 + m16) * 68 + kkW]);
                acc[0][ct] = __builtin_amdgcn_mfma_f32_16x16x32_bf16(a0, bf, acc[0][ct], 0, 0, 0);
                acc[1][ct] = __builtin_amdgcn_mfma_f32_16x16x32_bf16(a1, bf, acc[1][ct], 0, 0, 0);
            }
        }
        __syncthreads();                            // reads done before restage/alias
    }

    // Alias epilogue scratch into lA (dead after pass 2):
    //   lseg: [0..4095] u32 (max 2048 | min 2048) = 16 KB
    //   sSum: lA elems [8192..9215] (4x128 f32), sSq: [9216..10239]
    unsigned int* lseg = (unsigned int*)lA;
    float* sSum = (float*)&lA[8192];
    float* sSq  = (float*)&lA[9216];
    for (int i = tid; i < 2048; i += 256) {
        lseg[i] = 0u;
        lseg[i + 2048] = 0x7f7f7f7fu;
    }
    __syncthreads();

    const int g_first = sB[0];
    int nvalid = NN - row0; nvalid = nvalid > 128 ? 128 : nvalid;
    const int nseg = sB[nvalid - 1] - g_first + 1;
    const bool ldsok = (nseg <= MAXSEG);

    // Epilogue: m = relu(M2 + b2) -> hout (bf16, iff WRH), col sum/sumsq,
    // per-segment max/min (m>=0: float bits monotone under uint atomics).
    float csum[8] = {}, csq[8] = {};
    #pragma unroll
    for (int rt = 0; rt < 2; ++rt) {
        int lbase = wave * 32 + rt * 16 + quad * 4;
        int rbase = row0 + lbase;
        #pragma unroll
        for (int ct = 0; ct < 8; ++ct) {
            int col = ct * 16 + m16;
            float b = b2[col];
            int sprev = -1;
            float rmx = 0.f, rmn = 0.f;
            #pragma unroll
            for (int r = 0; r < 4; ++r) {
                int row = rbase + r;
                if (row < NN) {
                    float v = fmaxf(acc[rt][ct][r] + b, 0.0f);
                    if (WRH) hout[(long long)row * DD + col] = f2bfu(v);
                    csum[ct] += v;
                    csq[ct] += v * v;
                    int s = sB[lbase + r] - g_first;
                    if (s == sprev) {
                        rmx = fmaxf(rmx, v); rmn = fminf(rmn, v);
                    } else {
                        if (sprev >= 0) {
                            if (ldsok) {
                                atomicMax(&lseg[sprev * 128 + col], __float_as_uint(rmx));
                                atomicMin(&lseg[2048 + sprev * 128 + col], __float_as_uint(rmn));
                            } else {
                                atomicMax(&gmxl[(g_first + sprev) * DD + col], __float_as_uint(rmx));
                                atomicMin(&gmnl[(g_first + sprev) * DD + col], __float_as_uint(rmn));
                            }
                        }
                        sprev = s; rmx = v; rmn = v;
                    }
                }
            }
            if (sprev >= 0) {
                if (ldsok) {
                    atomicMax(&lseg[sprev * 128 + col], __float_as_uint(rmx));
                    atomicMin(&lseg[2048 + sprev * 128 + col], __float_as_uint(rmn));
                } else {
                    atomicMax(&gmxl[(g_first + sprev) * DD + col], __float_as_uint(rmx));
                    atomicMin(&gmnl[(g_first + sprev) * DD + col], __float_as_uint(rmn));
                }
            }
        }
    }
    #pragma unroll
    for (int ct = 0; ct < 8; ++ct) {
        csum[ct] += __shfl_xor(csum[ct], 16);
        csum[ct] += __shfl_xor(csum[ct], 32);
        csq[ct]  += __shfl_xor(csq[ct], 16);
        csq[ct]  += __shfl_xor(csq[ct], 32);
    }
    if (quad == 0) {
        #pragma unroll
        for (int ct = 0; ct < 8; ++ct) {
            int col = ct * 16 + m16;
            sSum[wave * 128 + col] = csum[ct];
            sSq[wave * 128 + col] = csq[ct];
        }
    }
    __syncthreads();    // lseg atomics + sSum/sSq visible
    if (ldsok) {
        for (int i = tid; i < nseg * 128; i += 256) {
            int s = i >> 7;
            int g = g_first + s, col = i & 127;
            unsigned int um = lseg[i], un = lseg[2048 + i];
            if (s > 0 && s < nseg - 1) {
                // interior segment: exclusively this block's rows -> plain store
                gmxl[g * DD + col] = um;
                gmnl[g * DD + col] = un;
            } else {
                if (um) atomicMax(&gmxl[g * DD + col], um);
                if (un != 0x7f7f7f7fu) atomicMin(&gmnl[g * DD + col], un);
            }
        }
    }
    if (tid < 128) {
        float* sp = statsP + ((blockIdx.x & (NSLOT - 1)) << 8);
        float s = sSum[tid] + sSum[128 + tid] + sSum[256 + tid] + sSum[384 + tid];
        float q = sSq[tid] + sSq[128 + tid] + sSq[256 + tid] + sSq[384 + tid];
        atomicAdd(&sp[tid], s);
        atomicAdd(&sp[DD + tid], q);
    }

    // Last-block fold: statsP (NSLOT x 256) -> stats (256). __syncthreads
    // drains this block's atomics (vmcnt(0) before s_barrier) so the counter
    // bump orders after them at L2; the last block therefore sees all slots.
    __syncthreads();
    if (tid == 0) {
        unsigned int t = atomicAdd((unsigned int*)dcnt, 1u);
        sLast = (t == (unsigned int)gridDim.x - 1u);
    }
    __syncthreads();
    if (sLast) {
        float a2 = 0.f;
        #pragma unroll 8
        for (int s2 = 0; s2 < NSLOT; ++s2)
            a2 += statsP[s2 * 256 + tid];
        stats[tid] = a2;
    }
}

// ---------------------------------------------------------------------------
// Final: out[g][l*DD+d] = a>=0 ? a*max(m)+c : a*min(m)+c  (0 if graph empty).
__global__ __launch_bounds__(256) void k_out(
    const float* __restrict__ stats, const float* __restrict__ gamma,
    const float* __restrict__ beta, const int* __restrict__ start,
    const unsigned int* __restrict__ gmx, const unsigned int* __restrict__ gmn,
    float* __restrict__ out)
{
    int idx = blockIdx.x * 256 + threadIdx.x;
    if (idx >= NL * NG * DD) return;
    int l = idx / (NG * DD);
    int rem = idx - l * NG * DD;
    int g = rem >> 7;
    int d = rem & 127;
    const float inv_n = 1.0f / (float)NN;
    float mean = stats[l * 256 + d] * inv_n;
    float var = stats[l * 256 + DD + d] * inv_n - mean * mean;
    float inv = rsqrtf(fmaxf(var, 0.f) + BN_EPS);
    float a = gamma[l * DD + d] * inv;
    float c = beta[l * DD + d] - mean * a;
    int n0 = start[g], n1 = start[g + 1];
    float res = 0.f;
    if (n1 > n0) {
        float mx = __uint_as_float(gmx[(l * NG + g) * DD + d]);
        float mn = __uint_as_float(gmn[(l * NG + g) * DD + d]);
        res = (a >= 0.f) ? fmaf(a, mx, c) : fmaf(a, mn, c);
    }
    out[(long long)g * (NL * DD) + l * DD + d] = res;
}

// ---------------------------------------------------------------------------
// Workspace layout (total 48,614,400 B — unchanged):
//   stats  @ 0          3,072 B (3 layers x 256 f32)  \
//   gcnt   @ 3,072        784 B (196 i32)              \ one memset
//   dcnt   @ 3,856         12 B (3 i32 done-counters)  / [0, 404,096)
//   cnt    @ 4,096    400,000 B (NN i32)              /
//   start  @ 405,504    8,196 B (2049 i32)
//   Wt     @ 417,792  196,608 B (6*128*128 bf16)
//   csr    @ 614,400  22,400,000 B (NN*CAP i32 buckets)
//   hb     @ 23,014,400  25,600,000 B (bf16 [NN,128])
// d_in[0] (x, 51.2 MB) reused stream-ordered after k_cvt:
//   aggf   @ +0          25,600,000 B (bf16 [NN,128], per-layer transient)
//   bins   @ +25,600,000  7,225,344 B (196 x 9216 u32; dead after k_csr)
//   gmx    @ +32,825,344  3,145,728 B (u32 float-bits [NL][NG][DD], memset 0)
//   gmn    @ +35,971,072  3,145,728 B (memset 0x7f -> ~3.4e38)
//   statsP @ +39,116,800    196,608 B (f32 [NL][NSLOT][256], memset 0)
extern "C" void kernel_launch(void* const* d_in, const int* in_sizes, int n_in,
                              void* d_out, int out_size, void* d_ws, size_t ws_size,
                              hipStream_t stream) {
    const float* x     = (const float*)d_in[0];
    const int*   ei    = (const int*)d_in[1];
    const int*   batch = (const int*)d_in[2];
    const float* W1    = (const float*)d_in[3];
    const float* b1    = (const float*)d_in[4];
    const float* W2    = (const float*)d_in[5];
    const float* b2    = (const float*)d_in[6];
    const float* gamma = (const float*)d_in[7];
    const float* beta  = (const float*)d_in[8];
    float* out = (float*)d_out;
    unsigned short* aggf   = (unsigned short*)d_in[0];
    unsigned int*   bins   = (unsigned int*)((char*)d_in[0] + 25600000);
    unsigned int*   gmx    = (unsigned int*)((char*)d_in[0] + 32825344);
    unsigned int*   gmn    = (unsigned int*)((char*)d_in[0] + 35971072);
    float*          statsP = (float*)((char*)d_in[0] + 39116800);

    char* p = (char*)d_ws;
    float*          stats = (float*)p;                 // 3 x 256 f32
    int*            gcnt  = (int*)(p + 3072);
    int*            dcnt  = (int*)(p + 3856);
    int*            cnt   = (int*)(p + 4096);
    int*            start = (int*)(p + 405504);
    unsigned short* Wt    = (unsigned short*)(p + 417792);
    int*            csr   = (int*)(p + 614400);
    unsigned short* hb    = (unsigned short*)(p + 23014400);

    hipMemsetAsync(p, 0, 404096, stream);   // stats + gcnt + dcnt + cnt
    k_cvt<<<(NN * DD / 4 + 255) / 256, 256, 0, stream>>>(x, hb);
    // x consumed: safe to claim gmx/gmn/statsP regions of d_in[0].
    hipMemsetAsync(gmx, 0x00, NL * NG * DD * 4, stream);
    hipMemsetAsync(gmn, 0x7f, NL * NG * DD * 4, stream);
    hipMemsetAsync(statsP, 0, NL * NSLOT * 256 * 4, stream);
    k_wtrans<<<(6 * DD * DD + 255) / 256, 256, 0, stream>>>(W1, W2, Wt);
    k_bounds<<<(NN + 255) / 256, 256, 0, stream>>>(batch, start);
    k_grp<<<(NE + 4095) / 4096, 256, 0, stream>>>(ei, gcnt, bins);
    k_csr<<<NGRP, 256, 0, stream>>>(gcnt, bins, cnt, csr);

    const int nblk = (NN + 127) / 128;
    for (int l = 0; l < NL; ++l) {
        float* stats_l  = stats + l * 256;
        float* statsP_l = statsP + l * NSLOT * 256;
        unsigned int* gmxl = gmx + l * NG * DD;
        unsigned int* gmnl = gmn + l * NG * DD;
        if (l == 0)
            k_agg<true><<<(NN + 15) / 16, 256, 0, stream>>>(
                hb, cnt, csr, aggf, nullptr, nullptr, nullptr);
        else
            k_agg<false><<<(NN + 15) / 16, 256, 0, stream>>>(
                hb, cnt, csr, aggf,
                stats + (l - 1) * 256, gamma + (l - 1) * DD, beta + (l - 1) * DD);
        if (l < NL - 1)
            k_mlp<true><<<nblk, 256, 0, stream>>>(
                aggf, hb, Wt + l * DD * DD, b1 + l * DD,
                Wt + (3 + l) * DD * DD, b2 + l * DD,
                statsP_l, stats_l, dcnt + l, batch, gmxl, gmnl);
        else
            k_mlp<false><<<nblk, 256, 0, stream>>>(
                aggf, hb, Wt + l * DD * DD, b1 + l * DD,
                Wt + (3 + l) * DD * DD, b2 + l * DD,
                statsP_l, stats_l, dcnt + l, batch, gmxl, gmnl);
    }
    k_out<<<(NL * NG * DD + 255) / 256, 256, 0, stream>>>(
        stats, gamma, beta, start, gmx, gmn, out);
}

// Round 14
// 471.343 us; speedup vs baseline: 1.0235x; 1.0235x over previous
//
#include <hip/hip_runtime.h>
#include <stdint.h>

#define NN 100000     // nodes
#define NE 1600000    // edges
#define DD 128        // feature dim
#define NL 3          // layers
#define NG 2048       // graphs
#define BN_EPS 1e-5f
#define CAP 56        // per-node bucket capacity (Poisson(16); P(deg>=56)*NN ~ 8e-9)
#define GSH 9         // node-group shift: 512 nodes per group
#define GSZ 512
#define NGRP 196      // ceil(NN/512)
#define GBINCAP 9216  // per-group edge bin capacity (mean 8192, sigma~90 -> +11 sigma)
#define MAXSEG 16     // max graph segments per 128-row MLP block (LDS path)
#define NSLOT 64      // stats partial slots (contention 782/64 ~ 12-deep)

typedef short s16x8 __attribute__((ext_vector_type(8)));
typedef float f32x4 __attribute__((ext_vector_type(4)));

__device__ __forceinline__ unsigned short f2bfu(float f) {
    union { float f; unsigned int i; } x; x.f = f;
    unsigned int r = x.i + 0x7fffu + ((x.i >> 16) & 1u);
    return (unsigned short)(r >> 16);
}
__device__ __forceinline__ float bfu2f(unsigned short u) {
    union { unsigned int i; float f; } x; x.i = ((unsigned int)u) << 16; return x.f;
}
__device__ __forceinline__ float uplo(unsigned int u) {
    union { unsigned int i; float f; } x; x.i = u << 16; return x.f;
}
__device__ __forceinline__ float uphi(unsigned int u) {
    union { unsigned int i; float f; } x; x.i = u & 0xffff0000u; return x.f;
}
__device__ __forceinline__ void add8(float* a, uint4 v) {
    a[0] += uplo(v.x); a[1] += uphi(v.x);
    a[2] += uplo(v.y); a[3] += uphi(v.y);
    a[4] += uplo(v.z); a[5] += uphi(v.z);
    a[6] += uplo(v.w); a[7] += uphi(v.w);
}
__device__ __forceinline__ unsigned int pack2(float a, float b) {
    return (unsigned int)f2bfu(a) | ((unsigned int)f2bfu(b) << 16);
}

// ---------------------------------------------------------------------------
// One-time: x (f32) -> hb (bf16).
__global__ __launch_bounds__(256) void k_cvt(
    const float* __restrict__ x, unsigned short* __restrict__ hb)
{
    int i = (blockIdx.x * 256 + threadIdx.x) * 4;
    if (i >= NN * DD) return;
    float4 v = *(const float4*)(x + i);
    ushort4 o;
    o.x = f2bfu(v.x); o.y = f2bfu(v.y); o.z = f2bfu(v.z); o.w = f2bfu(v.w);
    *(ushort4*)(hb + i) = o;
}

// ---------------------------------------------------------------------------
// W1/W2 f32 [L][k][n] -> bf16 Wt[mat][n][k] (transposed for MFMA B operand).
__global__ __launch_bounds__(256) void k_wtrans(
    const float* __restrict__ W1, const float* __restrict__ W2,
    unsigned short* __restrict__ Wt)
{
    int idx = blockIdx.x * 256 + threadIdx.x;
    if (idx >= 6 * DD * DD) return;
    int mat = idx >> 14;
    int r = idx & 16383;
    int n = r >> 7, k = r & 127;
    const float* src = (mat < 3) ? (W1 + mat * DD * DD) : (W2 + (mat - 3) * DD * DD);
    Wt[idx] = f2bfu(src[k * DD + n]);
}

// ---------------------------------------------------------------------------
// batch (sorted int32) -> graph start offsets; start[NG] = NN.
__global__ __launch_bounds__(256) void k_bounds(
    const int* __restrict__ batch, int* __restrict__ start)
{
    int n = blockIdx.x * 256 + threadIdx.x;
    if (n >= NN) return;
    int bn = batch[n];
    bn = bn < 0 ? 0 : (bn > NG - 1 ? NG - 1 : bn);
    int bp;
    if (n == 0) bp = -1;
    else {
        bp = batch[n - 1];
        bp = bp < 0 ? 0 : (bp > NG - 1 ? NG - 1 : bp);
    }
    for (int g = bp + 1; g <= bn; ++g) start[g] = n;
    if (n == NN - 1) {
        for (int g = bn + 1; g <= NG; ++g) start[g] = NN;
    }
}

// ---------------------------------------------------------------------------
// Stage 1: single scan of ei; in-LDS counting sort of 4096 edges/block into
// NGRP node-groups; flush each group's edges as a CONTIGUOUS chunk at an
// atomically reserved offset. Packed record: (local_dst[9] << 17) | src[17].
__global__ __launch_bounds__(256) void k_grp(
    const int* __restrict__ ei, int* __restrict__ gcnt,
    unsigned int* __restrict__ bins)
{
    __shared__ int hist[256];
    __shared__ int scn[256];
    __shared__ int exs[256];
    __shared__ int lofs[256];
    __shared__ int gbase[256];
    __shared__ unsigned int stage[4096];
    const int tid = threadIdx.x;
    hist[tid] = 0;
    __syncthreads();

    // Phase A: load 16 edges/thread, histogram groups.
    unsigned int pk[16];
    int gg[16];
    unsigned int vmask = 0;
    #pragma unroll
    for (int q = 0; q < 4; ++q) {
        long long e0 = (long long)blockIdx.x * 4096 + q * 1024 + tid * 4;
        if (e0 < NE) {     // NE % 4 == 0: quad fully in range
            const int* dp = ei + NE + e0;
            const int* sp = ei + e0;
            int dd_[4], ss_[4];
            dd_[0] = __builtin_nontemporal_load(dp + 0);
            dd_[1] = __builtin_nontemporal_load(dp + 1);
            dd_[2] = __builtin_nontemporal_load(dp + 2);
            dd_[3] = __builtin_nontemporal_load(dp + 3);
            ss_[0] = __builtin_nontemporal_load(sp + 0);
            ss_[1] = __builtin_nontemporal_load(sp + 1);
            ss_[2] = __builtin_nontemporal_load(sp + 2);
            ss_[3] = __builtin_nontemporal_load(sp + 3);
            #pragma unroll
            for (int i = 0; i < 4; ++i) {
                int dst = dd_[i], src = ss_[i];
                if ((unsigned)dst < NN && (unsigned)src < NN) {
                    int g = dst >> GSH;
                    int j = q * 4 + i;
                    pk[j] = ((unsigned)(dst & (GSZ - 1)) << 17) | (unsigned)src;
                    gg[j] = g;
                    atomicAdd(&hist[g], 1);
                    vmask |= 1u << j;
                }
            }
        }
    }
    __syncthreads();

    // Phase B: exclusive prefix over 256 group counters (Hillis-Steele).
    int v = hist[tid];
    scn[tid] = v;
    __syncthreads();
    #pragma unroll
    for (int off = 1; off < 256; off <<= 1) {
        int t = (tid >= off) ? scn[tid - off] : 0;
        __syncthreads();
        scn[tid] += t;
        __syncthreads();
    }
    int ex = scn[tid] - v;
    exs[tid] = ex;
    lofs[tid] = ex;
    if (tid < NGRP) {
        gbase[tid] = hist[tid] ? atomicAdd(&gcnt[tid], hist[tid]) : 0;
    }
    __syncthreads();

    // Phase C: scatter into LDS staging (group-sorted order).
    #pragma unroll
    for (int j = 0; j < 16; ++j) {
        if (vmask & (1u << j)) {
            int p = atomicAdd(&lofs[gg[j]], 1);
            stage[p] = pk[j];
        }
    }
    __syncthreads();

    // Phase D: per-wave coalesced chunk flush, one group at a time.
    const int wave = tid >> 6, lane = tid & 63;
    for (int g = wave; g < NGRP; g += 4) {
        int len = hist[g];
        if (!len) continue;
        int gb = gbase[g], pb = exs[g];
        for (int k = lane; k < len; k += 64) {
            int o = gb + k;
            if (o < GBINCAP)
                bins[(long long)g * GBINCAP + o] = stage[pb + k];
        }
    }
}

// ---------------------------------------------------------------------------
// Stage 2: one block per 512-node group. Bucket fill entirely in LDS; global
// side is a coalesced bin read + fully coalesced csr region write.
__global__ __launch_bounds__(256, 1) void k_csr(
    const int* __restrict__ gcnt, const unsigned int* __restrict__ bins,
    int* __restrict__ cnt, int* __restrict__ csr)
{
    __shared__ int lcnt[GSZ];
    __shared__ int lcsr[GSZ * CAP];    // 512*56*4 = 114,688 B
    const int g = blockIdx.x;
    const int tid = threadIdx.x;
    for (int i = tid; i < GSZ; i += 256) lcnt[i] = 0;
    __syncthreads();

    int count = gcnt[g];
    count = count > GBINCAP ? GBINCAP : count;
    const unsigned int* bp = bins + (long long)g * GBINCAP;
    for (int e = tid * 4; e < count; e += 1024) {
        if (e + 4 <= count) {
            uint4 q4;
            q4.x = __builtin_nontemporal_load(bp + e + 0);
            q4.y = __builtin_nontemporal_load(bp + e + 1);
            q4.z = __builtin_nontemporal_load(bp + e + 2);
            q4.w = __builtin_nontemporal_load(bp + e + 3);
            unsigned int u[4] = {q4.x, q4.y, q4.z, q4.w};
            #pragma unroll
            for (int i = 0; i < 4; ++i) {
                int local = (int)(u[i] >> 17);
                int src = (int)(u[i] & 0x1FFFFu);
                int pos = atomicAdd(&lcnt[local], 1);
                if (pos < CAP) lcsr[local * CAP + pos] = src;
            }
        } else {
            for (int i = e; i < count; ++i) {
                unsigned int u = bp[i];
                int local = (int)(u >> 17);
                int src = (int)(u & 0x1FFFFu);
                int pos = atomicAdd(&lcnt[local], 1);
                if (pos < CAP) lcsr[local * CAP + pos] = src;
            }
        }
    }
    __syncthreads();

    const int nbase = g << GSH;
    int nmax = NN - nbase;
    nmax = nmax > GSZ ? GSZ : nmax;
    for (int i = tid; i < nmax; i += 256) cnt[nbase + i] = lcnt[i];
    const int tot = nmax * CAP;            // multiple of 4 (CAP=56)
    int* dstp = csr + (long long)nbase * CAP;
    for (int i = tid * 4; i < tot; i += 1024)
        *(int4*)(dstp + i) = *(const int4*)(&lcsr[i]);
}

// ---------------------------------------------------------------------------
// Gather-aggregate with BN-affine fold. 16-deep load batches (round-5 proven).
template <bool L0>
__global__ __launch_bounds__(256) void k_agg(
    const unsigned short* __restrict__ hb, const int* __restrict__ cnt,
    const int* __restrict__ csr, unsigned short* __restrict__ aggf,
    const float* __restrict__ stats_prev, const float* __restrict__ gamma_prev,
    const float* __restrict__ beta_prev)
{
    const int node = blockIdx.x * 16 + (threadIdx.x >> 4);
    const int lane = threadIdx.x & 15;
    if (node >= NN) return;
    int deg = cnt[node];
    deg = deg > CAP ? CAP : deg;
    const int* bkt = csr + node * CAP;
    const unsigned short* base = hb + lane * 8;
    float self8[8], acc[8];
    {
        uint4 v = *(const uint4*)(base + (long long)node * DD);   // self
        self8[0] = uplo(v.x); self8[1] = uphi(v.x);
        self8[2] = uplo(v.y); self8[3] = uphi(v.y);
        self8[4] = uplo(v.z); self8[5] = uphi(v.z);
        self8[6] = uplo(v.w); self8[7] = uphi(v.w);
        #pragma unroll
        for (int j = 0; j < 8; ++j) acc[j] = self8[j];
    }
    const int nb = (deg + 15) >> 4;
    for (int b = 0; b < nb; ++b) {
        const int e0 = b * 16;
        // NOTE: may read up to bkt[63] (past CAP for deg>=49); lands in the
        // following csr bucket — safe, and those indices are never used.
        int4 i0 = *(const int4*)(bkt + e0);
        int4 i1 = *(const int4*)(bkt + e0 + 4);
        int4 i2 = *(const int4*)(bkt + e0 + 8);
        int4 i3 = *(const int4*)(bkt + e0 + 12);
        int idx[16] = {i0.x, i0.y, i0.z, i0.w, i1.x, i1.y, i1.z, i1.w,
                       i2.x, i2.y, i2.z, i2.w, i3.x, i3.y, i3.z, i3.w};
        uint4 v[16];
        #pragma unroll
        for (int i = 0; i < 16; ++i) {
            int id = (e0 + i < deg) ? idx[i] : node;
            v[i] = *(const uint4*)(base + (long long)id * DD);
        }
        #pragma unroll
        for (int i = 0; i < 16; ++i) add8(acc, v[i]);
    }
    int pad = nb * 16 - deg;
    if (pad) {
        float pf = (float)pad;
        #pragma unroll
        for (int j = 0; j < 8; ++j) acc[j] = fmaf(-pf, self8[j], acc[j]);
    }
    if (!L0) {
        const float inv_n = 1.0f / (float)NN;
        const float dp1 = (float)(deg + 1);
        #pragma unroll
        for (int j = 0; j < 8; ++j) {
            int d = lane * 8 + j;
            float mean = stats_prev[d] * inv_n;
            float var = stats_prev[DD + d] * inv_n - mean * mean;
            float inv = rsqrtf(fmaxf(var, 0.f) + BN_EPS);
            float a = gamma_prev[d] * inv;
            float c = beta_prev[d] - mean * a;
            acc[j] = a * acc[j] + c * dp1;
        }
    }
    uint4 o;
    o.x = pack2(acc[0], acc[1]);
    o.y = pack2(acc[2], acc[3]);
    o.z = pack2(acc[4], acc[5]);
    o.w = pack2(acc[6], acc[7]);
    *(uint4*)(aggf + (long long)node * DD + lane * 8) = o;
}

// ---------------------------------------------------------------------------
// Fused MLP + BN stats + per-graph segment max/min (round-12 proven, 471.9us):
//  - statsP[bid&63][256] slot atomics (12-deep contention); k_red folds.
//  - gmx/gmn interior segments (block-exclusive, batch sorted) -> plain stores.
template <bool WRH>
__global__ __launch_bounds__(256, 3) void k_mlp(
    const unsigned short* __restrict__ aggf, unsigned short* __restrict__ hout,
    const unsigned short* __restrict__ W1t, const float* __restrict__ b1,
    const unsigned short* __restrict__ W2t, const float* __restrict__ b2,
    float* __restrict__ statsP, const int* __restrict__ batch,
    unsigned int* __restrict__ gmxl, unsigned int* __restrict__ gmnl)
{
    __shared__ unsigned short lA[128 * 136];   // 34,816 B (+8 pad rows)
    __shared__ unsigned short lW[128 * 68];    // 17,408 B: half-K W tile
    __shared__ int sB[128];
    const int tid = threadIdx.x;
    const int row0 = blockIdx.x * 128;

    if (tid < 128) {
        int row = row0 + tid;
        int b = batch[row < NN ? row : NN - 1];
        b = b < 0 ? 0 : (b > NG - 1 ? NG - 1 : b);
        sB[tid] = b;
    }
    {   // A tile from aggf
        int col8 = tid & 15, rr = tid >> 4;
        #pragma unroll
        for (int it = 0; it < 8; ++it) {
            int r = rr + it * 16;
            int grow = row0 + r;
            uint4 v;
            if (grow < NN) {
                v = *(const uint4*)(aggf + (long long)grow * DD + col8 * 8);
            } else {
                v.x = v.y = v.z = v.w = 0;
            }
            *(uint4*)(&lA[r * 136 + col8 * 8]) = v;
        }
    }

    const int wave = tid >> 6, lane = tid & 63;
    const int quad = lane >> 4, m16 = lane & 15;

    // ---- pass 1: M1 = A @ W1 (two half-K stages) ----
    f32x4 acc[2][8] = {};
    #pragma unroll
    for (int kh = 0; kh < 2; ++kh) {
        #pragma unroll
        for (int it = 0; it < 4; ++it) {            // stage 128x64 half of W1
            int eidx = (it * 256 + tid) * 8;        // 0..8191
            int r = eidx >> 6, c = eidx & 63;
            *(uint4*)(&lW[r * 68 + c]) = *(const uint4*)(W1t + r * DD + kh * 64 + c);
        }
        __syncthreads();                            // staging (and A tile) ready
        #pragma unroll
        for (int k0i = 0; k0i < 2; ++k0i) {
            const int kkA = kh * 64 + k0i * 32 + quad * 8;
            const int kkW = k0i * 32 + quad * 8;
            s16x8 a0 = *(const s16x8*)(&lA[(wave * 32 + m16) * 136 + kkA]);
            s16x8 a1 = *(const s16x8*)(&lA[(wave * 32 + 16 + m16) * 136 + kkA]);
            #pragma unroll
            for (int ct = 0; ct < 8; ++ct) {
                s16x8 bf = *(const s16x8*)(&lW[(ct * 16 + m16) * 68 + kkW]);
                acc[0][ct] = __builtin_amdgcn_mfma_f32_16x16x32_bf16(a0, bf, acc[0][ct], 0, 0, 0);
                acc[1][ct] = __builtin_amdgcn_mfma_f32_16x16x32_bf16(a1, bf, acc[1][ct], 0, 0, 0);
            }
        }
        __syncthreads();                            // reads done before restage
    }

    // relu(M1 + b1) back into lA. C/D map: col = lane&15, row = quad*4 + reg.
    #pragma unroll
    for (int rt = 0; rt < 2; ++rt) {
        #pragma unroll
        for (int ct = 0; ct < 8; ++ct) {
            int col = ct * 16 + m16;
            float b = b1[col];
            #pragma unroll
            for (int r = 0; r < 4; ++r) {
                int lrow = wave * 32 + rt * 16 + quad * 4 + r;
                lA[lrow * 136 + col] = f2bfu(fmaxf(acc[rt][ct][r] + b, 0.0f));
            }
        }
    }

    // ---- pass 2: M2 = M1 @ W2 (two half-K stages) ----
    #pragma unroll
    for (int rt = 0; rt < 2; ++rt)
        #pragma unroll
        for (int ct = 0; ct < 8; ++ct)
            acc[rt][ct] = f32x4{0.f, 0.f, 0.f, 0.f};
    #pragma unroll
    for (int kh = 0; kh < 2; ++kh) {
        #pragma unroll
        for (int it = 0; it < 4; ++it) {            // stage 128x64 half of W2
            int eidx = (it * 256 + tid) * 8;
            int r = eidx >> 6, c = eidx & 63;
            *(uint4*)(&lW[r * 68 + c]) = *(const uint4*)(W2t + r * DD + kh * 64 + c);
        }
        __syncthreads();                            // staging + (kh=0) relu-writes ready
        #pragma unroll
        for (int k0i = 0; k0i < 2; ++k0i) {
            const int kkA = kh * 64 + k0i * 32 + quad * 8;
            const int kkW = k0i * 32 + quad * 8;
            s16x8 a0 = *(const s16x8*)(&lA[(wave * 32 + m16) * 136 + kkA]);
            s16x8 a1 = *(const s16x8*)(&lA[(wave * 32 + 16 + m16) * 136 + kkA]);
            #pragma unroll
            for (int ct = 0; ct < 8; ++ct) {
                s16x8 bf = *(const s16x8*)(&lW[(ct * 16 + m16) * 68 + kkW]);
                acc[0][ct] = __builtin_amdgcn_mfma_f32_16x16x32_bf16(a0, bf, acc[0][ct], 0, 0, 0);
                acc[1][ct] = __builtin_amdgcn_mfma_f32_16x16x32_bf16(a1, bf, acc[1][ct], 0, 0, 0);
            }
        }
        __syncthreads();                            // reads done before restage/alias
    }

    // Alias epilogue scratch into lA (dead after pass 2):
    //   lseg: [0..4095] u32 (max 2048 | min 2048) = 16 KB
    //   sSum: lA elems [8192..9215] (4x128 f32), sSq: [9216..10239]
    unsigned int* lseg = (unsigned int*)lA;
    float* sSum = (float*)&lA[8192];
    float* sSq  = (float*)&lA[9216];
    for (int i = tid; i < 2048; i += 256) {
        lseg[i] = 0u;
        lseg[i + 2048] = 0x7f7f7f7fu;
    }
    __syncthreads();

    const int g_first = sB[0];
    int nvalid = NN - row0; nvalid = nvalid > 128 ? 128 : nvalid;
    const int nseg = sB[nvalid - 1] - g_first + 1;
    const bool ldsok = (nseg <= MAXSEG);

    // Epilogue: m = relu(M2 + b2) -> hout (bf16, iff WRH), col sum/sumsq,
    // per-segment max/min (m>=0: float bits monotone under uint atomics).
    float csum[8] = {}, csq[8] = {};
    #pragma unroll
    for (int rt = 0; rt < 2; ++rt) {
        int lbase = wave * 32 + rt * 16 + quad * 4;
        int rbase = row0 + lbase;
        #pragma unroll
        for (int ct = 0; ct < 8; ++ct) {
            int col = ct * 16 + m16;
            float b = b2[col];
            int sprev = -1;
            float rmx = 0.f, rmn = 0.f;
            #pragma unroll
            for (int r = 0; r < 4; ++r) {
                int row = rbase + r;
                if (row < NN) {
                    float v = fmaxf(acc[rt][ct][r] + b, 0.0f);
                    if (WRH) hout[(long long)row * DD + col] = f2bfu(v);
                    csum[ct] += v;
                    csq[ct] += v * v;
                    int s = sB[lbase + r] - g_first;
                    if (s == sprev) {
                        rmx = fmaxf(rmx, v); rmn = fminf(rmn, v);
                    } else {
                        if (sprev >= 0) {
                            if (ldsok) {
                                atomicMax(&lseg[sprev * 128 + col], __float_as_uint(rmx));
                                atomicMin(&lseg[2048 + sprev * 128 + col], __float_as_uint(rmn));
                            } else {
                                atomicMax(&gmxl[(g_first + sprev) * DD + col], __float_as_uint(rmx));
                                atomicMin(&gmnl[(g_first + sprev) * DD + col], __float_as_uint(rmn));
                            }
                        }
                        sprev = s; rmx = v; rmn = v;
                    }
                }
            }
            if (sprev >= 0) {
                if (ldsok) {
                    atomicMax(&lseg[sprev * 128 + col], __float_as_uint(rmx));
                    atomicMin(&lseg[2048 + sprev * 128 + col], __float_as_uint(rmn));
                } else {
                    atomicMax(&gmxl[(g_first + sprev) * DD + col], __float_as_uint(rmx));
                    atomicMin(&gmnl[(g_first + sprev) * DD + col], __float_as_uint(rmn));
                }
            }
        }
    }
    #pragma unroll
    for (int ct = 0; ct < 8; ++ct) {
        csum[ct] += __shfl_xor(csum[ct], 16);
        csum[ct] += __shfl_xor(csum[ct], 32);
        csq[ct]  += __shfl_xor(csq[ct], 16);
        csq[ct]  += __shfl_xor(csq[ct], 32);
    }
    if (quad == 0) {
        #pragma unroll
        for (int ct = 0; ct < 8; ++ct) {
            int col = ct * 16 + m16;
            sSum[wave * 128 + col] = csum[ct];
            sSq[wave * 128 + col] = csq[ct];
        }
    }
    __syncthreads();    // lseg atomics + sSum/sSq visible
    if (ldsok) {
        for (int i = tid; i < nseg * 128; i += 256) {
            int s = i >> 7;
            int g = g_first + s, col = i & 127;
            unsigned int um = lseg[i], un = lseg[2048 + i];
            if (s > 0 && s < nseg - 1) {
                // interior segment: exclusively this block's rows -> plain store
                gmxl[g * DD + col] = um;
                gmnl[g * DD + col] = un;
            } else {
                if (um) atomicMax(&gmxl[g * DD + col], um);
                if (un != 0x7f7f7f7fu) atomicMin(&gmnl[g * DD + col], un);
            }
        }
    }
    if (tid < 128) {
        float* sp = statsP + ((blockIdx.x & (NSLOT - 1)) << 8);
        float s = sSum[tid] + sSum[128 + tid] + sSum[256 + tid] + sSum[384 + tid];
        float q = sSq[tid] + sSq[128 + tid] + sSq[256 + tid] + sSq[384 + tid];
        atomicAdd(&sp[tid], s);
        atomicAdd(&sp[DD + tid], q);
    }
}

// ---------------------------------------------------------------------------
// Fold NSLOT stats partials -> stats[l] (256 f32). One block; coalesced rows.
__global__ __launch_bounds__(256) void k_red(
    const float* __restrict__ sp, float* __restrict__ statsL)
{
    float acc = 0.f;
    #pragma unroll 8
    for (int s2 = 0; s2 < NSLOT; ++s2)
        acc += sp[s2 * 256 + threadIdx.x];
    statsL[threadIdx.x] = acc;
}

// ---------------------------------------------------------------------------
// Final: out[g][l*DD+d] = a>=0 ? a*max(m)+c : a*min(m)+c  (0 if graph empty).
__global__ __launch_bounds__(256) void k_out(
    const float* __restrict__ stats, const float* __restrict__ gamma,
    const float* __restrict__ beta, const int* __restrict__ start,
    const unsigned int* __restrict__ gmx, const unsigned int* __restrict__ gmn,
    float* __restrict__ out)
{
    int idx = blockIdx.x * 256 + threadIdx.x;
    if (idx >= NL * NG * DD) return;
    int l = idx / (NG * DD);
    int rem = idx - l * NG * DD;
    int g = rem >> 7;
    int d = rem & 127;
    const float inv_n = 1.0f / (float)NN;
    float mean = stats[l * 256 + d] * inv_n;
    float var = stats[l * 256 + DD + d] * inv_n - mean * mean;
    float inv = rsqrtf(fmaxf(var, 0.f) + BN_EPS);
    float a = gamma[l * DD + d] * inv;
    float c = beta[l * DD + d] - mean * a;
    int n0 = start[g], n1 = start[g + 1];
    float res = 0.f;
    if (n1 > n0) {
        float mx = __uint_as_float(gmx[(l * NG + g) * DD + d]);
        float mn = __uint_as_float(gmn[(l * NG + g) * DD + d]);
        res = (a >= 0.f) ? fmaf(a, mx, c) : fmaf(a, mn, c);
    }
    out[(long long)g * (NL * DD) + l * DD + d] = res;
}

// ---------------------------------------------------------------------------
// Workspace layout (total 48,614,400 B — unchanged):
//   stats  @ 0          3,072 B (3 layers x 256 f32)  \
//   gcnt   @ 3,072        784 B (196 i32)              } one memset [0, 404,096)
//   cnt    @ 4,096    400,000 B (NN i32)              /
//   start  @ 405,504    8,196 B (2049 i32)
//   Wt     @ 417,792  196,608 B (6*128*128 bf16)
//   csr    @ 614,400  22,400,000 B (NN*CAP i32 buckets)
//   hb     @ 23,014,400  25,600,000 B (bf16 [NN,128])
// d_in[0] (x, 51.2 MB) reused stream-ordered after k_cvt:
//   aggf   @ +0          25,600,000 B (bf16 [NN,128], per-layer transient)
//   bins   @ +25,600,000  7,225,344 B (196 x 9216 u32; dead after k_csr)
//   gmx    @ +32,825,344  3,145,728 B (u32 float-bits [NL][NG][DD], memset 0)
//   gmn    @ +35,971,072  3,145,728 B (memset 0x7f -> ~3.4e38)
//   statsP @ +39,116,800    196,608 B (f32 [NL][NSLOT][256], memset 0)
extern "C" void kernel_launch(void* const* d_in, const int* in_sizes, int n_in,
                              void* d_out, int out_size, void* d_ws, size_t ws_size,
                              hipStream_t stream) {
    const float* x     = (const float*)d_in[0];
    const int*   ei    = (const int*)d_in[1];
    const int*   batch = (const int*)d_in[2];
    const float* W1    = (const float*)d_in[3];
    const float* b1    = (const float*)d_in[4];
    const float* W2    = (const float*)d_in[5];
    const float* b2    = (const float*)d_in[6];
    const float* gamma = (const float*)d_in[7];
    const float* beta  = (const float*)d_in[8];
    float* out = (float*)d_out;
    unsigned short* aggf   = (unsigned short*)d_in[0];
    unsigned int*   bins   = (unsigned int*)((char*)d_in[0] + 25600000);
    unsigned int*   gmx    = (unsigned int*)((char*)d_in[0] + 32825344);
    unsigned int*   gmn    = (unsigned int*)((char*)d_in[0] + 35971072);
    float*          statsP = (float*)((char*)d_in[0] + 39116800);

    char* p = (char*)d_ws;
    float*          stats = (float*)p;                 // 3 x 256 f32
    int*            gcnt  = (int*)(p + 3072);
    int*            cnt   = (int*)(p + 4096);
    int*            start = (int*)(p + 405504);
    unsigned short* Wt    = (unsigned short*)(p + 417792);
    int*            csr   = (int*)(p + 614400);
    unsigned short* hb    = (unsigned short*)(p + 23014400);

    hipMemsetAsync(p, 0, 404096, stream);   // stats (all layers) + gcnt + cnt
    k_cvt<<<(NN * DD / 4 + 255) / 256, 256, 0, stream>>>(x, hb);
    // x consumed: safe to claim gmx/gmn/statsP regions of d_in[0].
    hipMemsetAsync(gmx, 0x00, NL * NG * DD * 4, stream);
    hipMemsetAsync(gmn, 0x7f, NL * NG * DD * 4, stream);
    hipMemsetAsync(statsP, 0, NL * NSLOT * 256 * 4, stream);
    k_wtrans<<<(6 * DD * DD + 255) / 256, 256, 0, stream>>>(W1, W2, Wt);
    k_bounds<<<(NN + 255) / 256, 256, 0, stream>>>(batch, start);
    k_grp<<<(NE + 4095) / 4096, 256, 0, stream>>>(ei, gcnt, bins);
    k_csr<<<NGRP, 256, 0, stream>>>(gcnt, bins, cnt, csr);

    const int nblk = (NN + 127) / 128;
    for (int l = 0; l < NL; ++l) {
        float* stats_l  = stats + l * 256;
        float* statsP_l = statsP + l * NSLOT * 256;
        unsigned int* gmxl = gmx + l * NG * DD;
        unsigned int* gmnl = gmn + l * NG * DD;
        if (l == 0)
            k_agg<true><<<(NN + 15) / 16, 256, 0, stream>>>(
                hb, cnt, csr, aggf, nullptr, nullptr, nullptr);
        else
            k_agg<false><<<(NN + 15) / 16, 256, 0, stream>>>(
                hb, cnt, csr, aggf,
                stats + (l - 1) * 256, gamma + (l - 1) * DD, beta + (l - 1) * DD);
        if (l < NL - 1)
            k_mlp<true><<<nblk, 256, 0, stream>>>(
                aggf, hb, Wt + l * DD * DD, b1 + l * DD,
                Wt + (3 + l) * DD * DD, b2 + l * DD,
                statsP_l, batch, gmxl, gmnl);
        else
            k_mlp<false><<<nblk, 256, 0, stream>>>(
                aggf, hb, Wt + l * DD * DD, b1 + l * DD,
                Wt + (3 + l) * DD * DD, b2 + l * DD,
                statsP_l, batch, gmxl, gmnl);
        k_red<<<1, 256, 0, stream>>>(statsP_l, stats_l);
    }
    k_out<<<(NL * NG * DD + 255) / 256, 256, 0, stream>>>(
        stats, gamma, beta, start, gmx, gmn, out);
}